// Round 12
// baseline (4148.912 us; speedup 1.0000x reference)
//
#include <hip/hip_runtime.h>
#include <cstdint>
#include <cstddef>

typedef _Float16 half8  __attribute__((ext_vector_type(8)));
typedef _Float16 half2v __attribute__((ext_vector_type(2)));
typedef float    floatx4 __attribute__((ext_vector_type(4)));
typedef unsigned long long ull;

#define B_  64
#define T_  512
#define D_  512
#define H_  512
#define NG  2048   // 4*H

#if defined(__has_builtin)
#if __has_builtin(__builtin_amdgcn_fdot2)
#define HAVE_FDOT2 1
#endif
#endif

static __device__ __forceinline__ float fdot2_acc(half2v a, half2v b, float c) {
#ifdef HAVE_FDOT2
  return __builtin_amdgcn_fdot2(a, b, c, false);
#else
  return fmaf((float)a[0], (float)b[0], fmaf((float)a[1], (float)b[1], c));
#endif
}
static __device__ __forceinline__ half2v h2(half8 v, int i) {
  half2v r; r[0] = v[2*i]; r[1] = v[2*i+1]; return r;
}
static __device__ __forceinline__ float fast_sigmoid(float x) {
  return 1.0f / (1.0f + __expf(-x));
}
static __device__ __forceinline__ float fast_tanh(float x) {
  x = fminf(15.0f, fmaxf(-15.0f, x));
  float e = __expf(2.0f * x);
  return (e - 1.0f) / (e + 1.0f);
}

// LDS-only barrier: drains lgkmcnt but NOT vmcnt (global ops stay in flight
// across it — this is what lets preloaded polls ride under the phases).
#define LDS_BARRIER() do {                                   \
    asm volatile("s_waitcnt lgkmcnt(0)" ::: "memory");       \
    __builtin_amdgcn_s_barrier();                            \
  } while (0)

#define TAGMASK 0x0000FFFF0000FFFFull

// XG2 permuted layout: idx = t*131072 + grp*16384 + s*8192 + member*256
//                            + w*64 + lane,  lane = jjl*16 + g*4 + b
static __device__ __forceinline__ size_t xg2_idx(int t, int grp, int s,
                                                 int member, int w, int lane) {
  return (size_t)t*131072u + (unsigned)(grp*16384 + s*8192 + member*256
                                        + w*64 + lane);
}

// ---------------------------------------------------------------------------
// Kernel 1: input projections (epilogue now writes permuted XG2)
// ---------------------------------------------------------------------------
__global__ __launch_bounds__(256) void proj_kernel(
    const float* __restrict__ x,
    const float* __restrict__ Wc, const float* __restrict__ Wi,
    const float* __restrict__ Wf, const float* __restrict__ Wo,
    const float* __restrict__ bc, const float* __restrict__ bi,
    const float* __restrict__ bf2, const float* __restrict__ bo,
    _Float16* __restrict__ XG2)
{
  const int tiles_n = NG / 64;
  int tM = blockIdx.x / tiles_n;
  int tN = blockIdx.x % tiles_n;
  int r0 = tM * 64;
  int t0 = r0 >> 6;
  int n0 = tN * 64;
  int g  = n0 >> 9;
  const float* W    = (g==0) ? Wc : (g==1) ? Wi : (g==2) ? Wf : Wo;
  const float* bias = (g==0) ? bc : (g==1) ? bi : (g==2) ? bf2 : bo;
  int j0 = n0 & (H_-1);

  __shared__ _Float16 Al[64*40];
  __shared__ _Float16 Bl[64*40];

  int tid  = threadIdx.x;
  int wave = tid >> 6;
  int lane = tid & 63;

  floatx4 acc[4] = {};

  int arow = tid >> 2;
  int ak0  = (tid & 3) * 8;
  const float* xsrc = x + ((size_t)arow * T_ + t0) * D_;

  int bcol = tid & 63;
  int bk0  = (tid >> 6) * 8;

  for (int k0 = 0; k0 < D_; k0 += 32) {
    half8 av;
    #pragma unroll
    for (int i = 0; i < 8; ++i) av[i] = (_Float16)xsrc[k0 + ak0 + i];
    *(half8*)&Al[arow*40 + ak0] = av;

    half8 bv;
    #pragma unroll
    for (int i = 0; i < 8; ++i)
      bv[i] = (_Float16)W[(size_t)(k0 + bk0 + i) * H_ + j0 + bcol];
    *(half8*)&Bl[bcol*40 + bk0] = bv;

    __syncthreads();

    half8 afrag = *(half8*)&Al[(wave*16 + (lane & 15))*40 + (lane >> 4)*8];
    #pragma unroll
    for (int ct = 0; ct < 4; ++ct) {
      half8 bfrag = *(half8*)&Bl[(ct*16 + (lane & 15))*40 + (lane >> 4)*8];
      acc[ct] = __builtin_amdgcn_mfma_f32_16x16x32_f16(afrag, bfrag, acc[ct], 0, 0, 0);
    }
    __syncthreads();
  }

  #pragma unroll
  for (int ct = 0; ct < 4; ++ct) {
    int col = n0 + ct*16 + (lane & 15);
    float bvs = bias[col & (H_-1)];
    int jfull  = col & (H_-1);
    int member = jfull >> 4;
    int jj     = jfull & 15;
    int w2     = jj >> 2;
    int jjl    = jj & 3;
    #pragma unroll
    for (int i = 0; i < 4; ++i) {
      int row   = r0 + wave*16 + (lane >> 4)*4 + i;
      int t     = row >> 6;
      int b_abs = row & 63;
      int grp   = b_abs >> 3;
      int b_in  = b_abs & 7;
      int s     = b_in >> 2;
      int bb    = b_in & 3;
      int lane2 = jjl*16 + g*4 + bb;
      XG2[xg2_idx(t, grp, s, member, w2, lane2)] = (_Float16)(acc[ct][i] + bvs);
    }
  }
}

// ---------------------------------------------------------------------------
// Kernel 2: persistent scan, v12.
//   - R11's 2-set pipeline, but poll loads PRELOADED one phase early:
//     phase A(t) issues set-B loads for t; phase B(t) issues set-A loads
//     for t+1. Checks become register tag-tests; MALL RT rides under the
//     opposite phase. dbuf load-before-store aliasing pins issue order.
//   - quad-broadcast dot mapping (lane = jjl*16+g*4+b): 4 lanes share each
//     U row -> U LDS traffic /4; gates combine via shfl_xor(4/8).
//   - XG2 permuted: per-wave contiguous 128B step-read, prefetched 1 step.
// ---------------------------------------------------------------------------
__global__ __launch_bounds__(256) void scan_kernel(
    const _Float16* __restrict__ XG2,
    const float* __restrict__ Uc, const float* __restrict__ Ui,
    const float* __restrict__ Uf, const float* __restrict__ Uo,
    float* __restrict__ out, unsigned* __restrict__ dbuf)
{
  extern __shared__ _Float16 lds[];
  _Float16* U2    = lds;            // [k8(64)][row(64)][8] halfs = 64 KB
  _Float16* h_lds = lds + 32768;    // [set(2)*4 + b][520] halfs = 8.1 KB

  int tid = threadIdx.x;
  int grp = blockIdx.x & 7;
  int member = blockIdx.x >> 3;
  int j0 = member * 16;

  { // one-time: stage U into quad-broadcast layout, f32 -> f16
    int jj = tid & 15;
    int kk = tid >> 4;   // 16 k-slots
    int r  = (jj >> 2)*16 + (jj & 3)*4;   // + g below
    #pragma unroll
    for (int g = 0; g < 4; ++g) {
      const float* U = (g==0) ? Uc : (g==1) ? Ui : (g==2) ? Uf : Uo;
      for (int k = kk; k < H_; k += 16)
        U2[((size_t)(k >> 3)*64 + r + g)*8 + (k & 7)] =
            (_Float16)U[(size_t)k * H_ + j0 + jj];
    }
  }
  __syncthreads();

  int lane = tid & 63;
  int w    = tid >> 6;
  int b    = lane & 3;            // batch within set
  int g    = (lane >> 2) & 3;    // gate (0=a,1=i,2=f,3=o)
  int jjl  = lane >> 4;          // 0..3
  int jj   = w*4 + jjl;
  int j    = j0 + jj;
  int uidx8 = w*16 + (lane >> 2);  // U2 half8 row for this lane's (jj,g)
  bool isg0 = (g == 0);

  // consumer staging: thread's 8 words = row cb, cols ccol..ccol+8
  int cb   = tid >> 6;
  int ccol = (tid & 63) * 8;

  int bgA = grp*8 + b;        // set A batch (s=0)
  int bgB = grp*8 + 4 + b;    // set B batch (s=1)

  float cA = 0.0f, cB = 0.0f;

  ull pwA[4], pwB[4];
  // prologue: preload set A for t=0 (memset tag 0 == h0=0, fresh)
  {
    const ull* a0 = (const ull*)dbuf + (size_t)((0*8 + grp))*1024u + tid*4;
    #pragma unroll
    for (int q = 0; q < 4; ++q)
      pwA[q] = __hip_atomic_load(a0 + q, __ATOMIC_RELAXED,
                                 __HIP_MEMORY_SCOPE_AGENT);
  }
  float xgA = (float)XG2[xg2_idx(0, grp, 0, member, w, lane)];
  float xgB = (float)XG2[xg2_idx(0, grp, 1, member, w, lane)];

  for (int t = 0; t < T_; ++t) {
    ull want2 = (ull)(unsigned)(t & 0xFFFF) * 0x0000000100000001ull;
    int tn = (t + 1 < T_) ? (t + 1) : t;

    // ================= PHASE A (set 0) =================
    {
      // check preloaded words; rare retry
      ull diff = 0;
      #pragma unroll
      for (int q = 0; q < 4; ++q) diff |= (pwA[q] ^ want2) & TAGMASK;
      if (diff) {
        const ull* src = (const ull*)dbuf
            + (size_t)(((0*2 + (t & 1))*8 + grp))*1024u + tid*4;
        do {
          #pragma unroll
          for (int q = 0; q < 4; ++q)
            pwA[q] = __hip_atomic_load(src + q, __ATOMIC_RELAXED,
                                       __HIP_MEMORY_SCOPE_AGENT);
          diff = 0;
          #pragma unroll
          for (int q = 0; q < 4; ++q) diff |= (pwA[q] ^ want2) & TAGMASK;
          if (diff) __builtin_amdgcn_s_sleep(1);
        } while (diff);
      }
      half8 hv;
      #pragma unroll
      for (int q = 0; q < 4; ++q) {
        hv[2*q]   = __builtin_bit_cast(_Float16, (unsigned short)((unsigned)pwA[q] >> 16));
        hv[2*q+1] = __builtin_bit_cast(_Float16, (unsigned short)(pwA[q] >> 48));
      }
      *(half8*)&h_lds[(0*4 + cb)*520 + ccol] = hv;
    }
    LDS_BARRIER();

    // issue set-B preloads for t (publish(B,t) happened in phase B(t-1))
    {
      const ull* nb = (const ull*)dbuf
          + (size_t)(((1*2 + (t & 1))*8 + grp))*1024u + tid*4;
      #pragma unroll
      for (int q = 0; q < 4; ++q)
        pwB[q] = __hip_atomic_load(nb + q, __ATOMIC_RELAXED,
                                   __HIP_MEMORY_SCOPE_AGENT);
    }
    float xgAn = (float)XG2[xg2_idx(tn, grp, 0, member, w, lane)];

    {
      // dot: h(set0, b) . U2row(jj,g) — 4 chains for ILP
      const half8* hb = (const half8*)&h_lds[(0*4 + b)*520];
      const half8* ub = (const half8*)U2;
      float a0 = 0.f, a1 = 0.f, a2 = 0.f, a3 = 0.f;
      #pragma unroll 8
      for (int k8 = 0; k8 < 64; ++k8) {
        half8 hv8 = hb[k8];
        half8 uv8 = ub[(size_t)k8*64 + uidx8];
        a0 = fdot2_acc(h2(hv8,0), h2(uv8,0), a0);
        a1 = fdot2_acc(h2(hv8,1), h2(uv8,1), a1);
        a2 = fdot2_acc(h2(hv8,2), h2(uv8,2), a2);
        a3 = fdot2_acc(h2(hv8,3), h2(uv8,3), a3);
      }
      float pre = ((a0 + a1) + (a2 + a3)) + xgA;

      float act = isg0 ? fast_tanh(pre) : fast_sigmoid(pre);
      float t4  = __shfl_xor(act, 4);    // g^1
      float ia  = act * t4;              // g0: tanh(a)*sig(i)
      float fv  = __shfl_xor(act, 8);    // g^2 -> g0: sig(f)
      float ov  = __shfl_xor(t4, 8);     // g0: sig(o)

      if (isg0) {
        cA = fmaf(fv, cA, ia);
        float hval = ov * fast_tanh(cA);
        if (t + 1 < T_) {
          unsigned wv = ((unsigned)__builtin_bit_cast(unsigned short,
                              (_Float16)hval) << 16)
                      | ((unsigned)(t + 1) & 0xFFFFu);
          unsigned widx = (unsigned)(((0*2 + ((t+1) & 1))*8 + grp))*2048u
                        + (unsigned)(b*512 + j);
          __hip_atomic_store(&dbuf[widx], wv,
                             __ATOMIC_RELAXED, __HIP_MEMORY_SCOPE_AGENT);
        }
        out[((size_t)bgA * T_ + t) * H_ + j] = hval;
      }
      xgA = xgAn;
    }

    // ================= PHASE B (set 1) =================
    {
      ull diff = 0;
      #pragma unroll
      for (int q = 0; q < 4; ++q) diff |= (pwB[q] ^ want2) & TAGMASK;
      if (diff) {
        const ull* src = (const ull*)dbuf
            + (size_t)(((1*2 + (t & 1))*8 + grp))*1024u + tid*4;
        do {
          #pragma unroll
          for (int q = 0; q < 4; ++q)
            pwB[q] = __hip_atomic_load(src + q, __ATOMIC_RELAXED,
                                       __HIP_MEMORY_SCOPE_AGENT);
          diff = 0;
          #pragma unroll
          for (int q = 0; q < 4; ++q) diff |= (pwB[q] ^ want2) & TAGMASK;
          if (diff) __builtin_amdgcn_s_sleep(1);
        } while (diff);
      }
      half8 hv;
      #pragma unroll
      for (int q = 0; q < 4; ++q) {
        hv[2*q]   = __builtin_bit_cast(_Float16, (unsigned short)((unsigned)pwB[q] >> 16));
        hv[2*q+1] = __builtin_bit_cast(_Float16, (unsigned short)(pwB[q] >> 48));
      }
      *(half8*)&h_lds[(1*4 + cb)*520 + ccol] = hv;
    }
    LDS_BARRIER();

    // issue set-A preloads for t+1 (publish(A,t+1) happened in phase A above)
    {
      const ull* na = (const ull*)dbuf
          + (size_t)(((0*2 + ((t+1) & 1))*8 + grp))*1024u + tid*4;
      #pragma unroll
      for (int q = 0; q < 4; ++q)
        pwA[q] = __hip_atomic_load(na + q, __ATOMIC_RELAXED,
                                   __HIP_MEMORY_SCOPE_AGENT);
    }
    float xgBn = (float)XG2[xg2_idx(tn, grp, 1, member, w, lane)];

    {
      const half8* hb = (const half8*)&h_lds[(1*4 + b)*520];
      const half8* ub = (const half8*)U2;
      float a0 = 0.f, a1 = 0.f, a2 = 0.f, a3 = 0.f;
      #pragma unroll 8
      for (int k8 = 0; k8 < 64; ++k8) {
        half8 hv8 = hb[k8];
        half8 uv8 = ub[(size_t)k8*64 + uidx8];
        a0 = fdot2_acc(h2(hv8,0), h2(uv8,0), a0);
        a1 = fdot2_acc(h2(hv8,1), h2(uv8,1), a1);
        a2 = fdot2_acc(h2(hv8,2), h2(uv8,2), a2);
        a3 = fdot2_acc(h2(hv8,3), h2(uv8,3), a3);
      }
      float pre = ((a0 + a1) + (a2 + a3)) + xgB;

      float act = isg0 ? fast_tanh(pre) : fast_sigmoid(pre);
      float t4  = __shfl_xor(act, 4);
      float ia  = act * t4;
      float fv  = __shfl_xor(act, 8);
      float ov  = __shfl_xor(t4, 8);

      if (isg0) {
        cB = fmaf(fv, cB, ia);
        float hval = ov * fast_tanh(cB);
        if (t + 1 < T_) {
          unsigned wv = ((unsigned)__builtin_bit_cast(unsigned short,
                              (_Float16)hval) << 16)
                      | ((unsigned)(t + 1) & 0xFFFFu);
          unsigned widx = (unsigned)(((1*2 + ((t+1) & 1))*8 + grp))*2048u
                        + (unsigned)(b*512 + j);
          __hip_atomic_store(&dbuf[widx], wv,
                             __ATOMIC_RELAXED, __HIP_MEMORY_SCOPE_AGENT);
        }
        out[((size_t)bgB * T_ + t) * H_ + j] = hval;
      }
      xgB = xgBn;
    }
  }
}

// ---------------------------------------------------------------------------
extern "C" void kernel_launch(void* const* d_in, const int* in_sizes, int n_in,
                              void* d_out, int out_size, void* d_ws, size_t ws_size,
                              hipStream_t stream)
{
  const float* x  = (const float*)d_in[0];
  const float* Wc = (const float*)d_in[1];
  const float* Wi = (const float*)d_in[2];
  const float* Wf = (const float*)d_in[3];
  const float* Wo = (const float*)d_in[4];
  const float* Uc = (const float*)d_in[5];
  const float* Ui = (const float*)d_in[6];
  const float* Uf = (const float*)d_in[7];
  const float* Uo = (const float*)d_in[8];
  const float* bc = (const float*)d_in[9];
  const float* bi = (const float*)d_in[10];
  const float* bf2= (const float*)d_in[11];
  const float* bo = (const float*)d_in[12];
  float* out = (float*)d_out;

  const size_t XG_BYTES = (size_t)T_ * B_ * NG * sizeof(_Float16);      // 128 MiB
  const size_t DB_BYTES = (size_t)2 * 2 * 8 * 2048 * sizeof(unsigned);  // 256 KiB

  if (ws_size < XG_BYTES + DB_BYTES) return;

  _Float16* XG2  = (_Float16*)d_ws;
  unsigned* dbuf = (unsigned*)((char*)d_ws + XG_BYTES);

  // tag 0 == "h^0 = 0 ready"; re-zeroed every launch (kills replay aliasing)
  (void)hipMemsetAsync(dbuf, 0, DB_BYTES, stream);

  proj_kernel<<<dim3((T_*B_/64) * (NG/64)), dim3(256), 0, stream>>>(
      x, Wc, Wi, Wf, Wo, bc, bi, bf2, bo, XG2);

  const int lds_bytes = (32768 + 8*520) * (int)sizeof(_Float16);  // 73,856 B
  (void)hipFuncSetAttribute(reinterpret_cast<const void*>(scan_kernel),
                      hipFuncAttributeMaxDynamicSharedMemorySize, lds_bytes);
  scan_kernel<<<dim3(256), dim3(256), lds_bytes, stream>>>(
      XG2, Uc, Ui, Uf, Uo, out, dbuf);
}

// Round 13
// 2060.287 us; speedup vs baseline: 2.0138x; 2.0138x over previous
//
#include <hip/hip_runtime.h>
#include <cstdint>
#include <cstddef>

typedef _Float16 half8  __attribute__((ext_vector_type(8)));
typedef float    floatx4 __attribute__((ext_vector_type(4)));
typedef unsigned long long ull;

#define B_  64
#define T_  512
#define D_  512
#define H_  512
#define NG  2048   // 4*H

static __device__ __forceinline__ float fast_sigmoid(float x) {
  return 1.0f / (1.0f + __expf(-x));
}
static __device__ __forceinline__ float fast_tanh(float x) {
  x = fminf(15.0f, fmaxf(-15.0f, x));
  float e = __expf(2.0f * x);
  return (e - 1.0f) / (e + 1.0f);
}

// LDS-only barrier: drains lgkmcnt but NOT vmcnt (global ops stay in flight).
#define LDS_BARRIER() do {                                   \
    asm volatile("s_waitcnt lgkmcnt(0)" ::: "memory");       \
    __builtin_amdgcn_s_barrier();                            \
  } while (0)

#define TAGMASK 0x0000FFFF0000FFFFull

// ---------------------------------------------------------------------------
// Kernel 1: input projections (unchanged R9 version — measured ~0.17 ms)
// ---------------------------------------------------------------------------
__global__ __launch_bounds__(256) void proj_kernel(
    const float* __restrict__ x,
    const float* __restrict__ Wc, const float* __restrict__ Wi,
    const float* __restrict__ Wf, const float* __restrict__ Wo,
    const float* __restrict__ bc, const float* __restrict__ bi,
    const float* __restrict__ bf2, const float* __restrict__ bo,
    _Float16* __restrict__ XG)
{
  const int tiles_n = NG / 64;
  int tM = blockIdx.x / tiles_n;
  int tN = blockIdx.x % tiles_n;
  int r0 = tM * 64;
  int t0 = r0 >> 6;
  int n0 = tN * 64;
  int g  = n0 >> 9;
  const float* W    = (g==0) ? Wc : (g==1) ? Wi : (g==2) ? Wf : Wo;
  const float* bias = (g==0) ? bc : (g==1) ? bi : (g==2) ? bf2 : bo;
  int j0 = n0 & (H_-1);

  __shared__ _Float16 Al[64*40];
  __shared__ _Float16 Bl[64*40];

  int tid  = threadIdx.x;
  int wave = tid >> 6;
  int lane = tid & 63;

  floatx4 acc[4] = {};

  int arow = tid >> 2;
  int ak0  = (tid & 3) * 8;
  const float* xsrc = x + ((size_t)arow * T_ + t0) * D_;

  int bcol = tid & 63;
  int bk0  = (tid >> 6) * 8;

  for (int k0 = 0; k0 < D_; k0 += 32) {
    half8 av;
    #pragma unroll
    for (int i = 0; i < 8; ++i) av[i] = (_Float16)xsrc[k0 + ak0 + i];
    *(half8*)&Al[arow*40 + ak0] = av;

    half8 bv;
    #pragma unroll
    for (int i = 0; i < 8; ++i)
      bv[i] = (_Float16)W[(size_t)(k0 + bk0 + i) * H_ + j0 + bcol];
    *(half8*)&Bl[bcol*40 + bk0] = bv;

    __syncthreads();

    half8 afrag = *(half8*)&Al[(wave*16 + (lane & 15))*40 + (lane >> 4)*8];
    #pragma unroll
    for (int ct = 0; ct < 4; ++ct) {
      half8 bfrag = *(half8*)&Bl[(ct*16 + (lane & 15))*40 + (lane >> 4)*8];
      acc[ct] = __builtin_amdgcn_mfma_f32_16x16x32_f16(afrag, bfrag, acc[ct], 0, 0, 0);
    }
    __syncthreads();
  }

  #pragma unroll
  for (int ct = 0; ct < 4; ++ct) {
    int col = n0 + ct*16 + (lane & 15);
    float bvs = bias[col & (H_-1)];
    #pragma unroll
    for (int i = 0; i < 4; ++i) {
      int row = r0 + wave*16 + (lane >> 4)*4 + i;
      XG[(size_t)row * NG + col] = (_Float16)(acc[ct][i] + bvs);
    }
  }
}

// ---------------------------------------------------------------------------
// Kernel 2: persistent scan, v13 — R9 sync fabric + MFMA recurrent dots.
//   Per WG-step GEMM: [16(8 real b)x512] x [512x64] via 16 MFMA/wave,
//   U fragments resident in VGPRs (step-invariant), h in 16KB LDS A-layout.
//   N-order col16 = jjl*4+g -> gate combine by shfl_xor(1/2), no act barrier.
//   Sync: R9's tagged words + masked-retry poll (compiler-emitted agent
//   atomics only). dbuf layout identical to R9. memset each launch.
// ---------------------------------------------------------------------------
__global__ __launch_bounds__(256) void scan_kernel(
    const _Float16* __restrict__ XG,
    const float* __restrict__ Uc, const float* __restrict__ Ui,
    const float* __restrict__ Uf, const float* __restrict__ Uo,
    float* __restrict__ out, unsigned* __restrict__ dbuf)
{
  __shared__ _Float16 h_lds[16*512];   // [ks(16)][row(16)][k32] halfs = 16 KB

  int tid = threadIdx.x;
  int grp = blockIdx.x & 7;
  int member = blockIdx.x >> 3;

  int lane = tid & 63;
  int w    = tid >> 6;            // wave = n-tile (4 cols x 4 gates)
  int c16  = lane & 15;           // n within tile = jjl*4 + g
  int sub  = lane >> 4;           // k-subchunk (input) / row-group (output)
  int g    = c16 & 3;
  int jjl  = c16 >> 2;
  int jcol = member*16 + w*4 + jjl;   // output column j
  int hi   = sub;                      // C row group: batches hi*4+i
  bool pub = (g == 0) && (hi < 2);

  // ---- one-time: U fragments -> VGPRs (B-frag: lane holds B[col][k8]) ----
  const float* Ug = (g==0) ? Uc : (g==1) ? Ui : (g==2) ? Uf : Uo;
  half8 uf[16];
  #pragma unroll
  for (int ks = 0; ks < 16; ++ks) {
    half8 v;
    #pragma unroll
    for (int q = 0; q < 8; ++q)
      v[q] = (_Float16)Ug[(size_t)(ks*32 + sub*8 + q) * H_ + jcol];
    uf[ks] = v;
  }

  // consumer staging: thread's 16 polled words = h[b=sb][k=sm*16..+16)
  int sm  = tid >> 3;             // source member
  int sb  = tid & 7;              // batch row
  _Float16* stg = &h_lds[(sm >> 1)*512 + sb*32 + (sm & 1)*16];

  const _Float16* abase = &h_lds[c16*32 + sub*8];   // + ks*512 per k-step

  floatx4 c4 = {0.f, 0.f, 0.f, 0.f};
  float xg[4] = {0.f, 0.f, 0.f, 0.f};
  #pragma unroll
  for (int i = 0; i < 4; ++i)
    if (hi < 2)
      xg[i] = (float)XG[(size_t)(grp*8 + hi*4 + i) * NG + g*512 + jcol];

  for (int t = 0; t < T_; ++t) {
    LDS_BARRIER();   // prev step's A-frag reads complete before overwrite

    // ---- poll h^t (R9 fabric: bulk read + masked retry) ----
    {
      const ull* src8 = (const ull*)dbuf
          + ((size_t)(t & 1))*16384u + (size_t)grp*2048u + (size_t)tid*8u;
      ull want2 = (ull)(unsigned)(t & 0xFFFF) * 0x0000000100000001ull;
      ull w8[8];
      unsigned pend = 0xFFu;
      for (;;) {
        #pragma unroll
        for (int q = 0; q < 8; ++q)
          if (pend & (1u << q))
            w8[q] = __hip_atomic_load(src8 + q, __ATOMIC_RELAXED,
                                      __HIP_MEMORY_SCOPE_AGENT);
        unsigned npend = 0;
        #pragma unroll
        for (int q = 0; q < 8; ++q)
          if ((pend & (1u << q)) && ((w8[q] ^ want2) & TAGMASK))
            npend |= 1u << q;
        if (!npend) break;
        pend = npend;
        __builtin_amdgcn_s_sleep(2);
      }
      half8 hv0, hv1;
      #pragma unroll
      for (int q = 0; q < 4; ++q) {
        hv0[2*q]   = __builtin_bit_cast(_Float16, (unsigned short)((unsigned)w8[q]   >> 16));
        hv0[2*q+1] = __builtin_bit_cast(_Float16, (unsigned short)(w8[q]   >> 48));
        hv1[2*q]   = __builtin_bit_cast(_Float16, (unsigned short)((unsigned)w8[4+q] >> 16));
        hv1[2*q+1] = __builtin_bit_cast(_Float16, (unsigned short)(w8[4+q] >> 48));
      }
      *(half8*)stg       = hv0;
      *(half8*)(stg + 8) = hv1;
    }
    LDS_BARRIER();   // staged h visible

    // ---- MFMA dot: acc[b][c16] = sum_k h[b][k] * U[k][col] ----
    floatx4 a0 = {0.f,0.f,0.f,0.f}, a1 = {0.f,0.f,0.f,0.f};
    #pragma unroll
    for (int ks = 0; ks < 16; ks += 2) {
      half8 af0 = *(const half8*)(abase + ks*512);
      a0 = __builtin_amdgcn_mfma_f32_16x16x32_f16(af0, uf[ks],   a0, 0, 0, 0);
      half8 af1 = *(const half8*)(abase + (ks+1)*512);
      a1 = __builtin_amdgcn_mfma_f32_16x16x32_f16(af1, uf[ks+1], a1, 0, 0, 0);
    }

    // ---- gates: intra-wave combine (g occupies lane bits 0-1) ----
    float hval[4];
    #pragma unroll
    for (int i = 0; i < 4; ++i) {
      float pre = (a0[i] + a1[i]) + xg[i];
      float act = (g == 0) ? fast_tanh(pre) : fast_sigmoid(pre);
      float t1  = __shfl_xor(act, 1);    // g0 <- act(g1)=sig(i)
      float ia  = act * t1;              // g0: tanh(a)*sig(i)
      float fv  = __shfl_xor(act, 2);    // g0 <- sig(f)
      float ov  = __shfl_xor(t1, 2);     // g0 <- sig(o)
      float cn  = fmaf(fv, c4[i], ia);
      c4[i] = cn;
      hval[i] = ov * fast_tanh(cn);
    }

    // ---- publish + out (g0, real rows only) ----
    if (pub) {
      if (t + 1 < T_) {
        #pragma unroll
        for (int i = 0; i < 4; ++i) {
          unsigned wv = ((unsigned)__builtin_bit_cast(unsigned short,
                              (_Float16)hval[i]) << 16)
                      | ((unsigned)(t + 1) & 0xFFFFu);
          unsigned widx = ((unsigned)((t + 1) & 1))*32768u + (unsigned)grp*4096u
                        + (unsigned)member*128u
                        + (unsigned)((hi*4 + i)*16 + w*4 + jjl);
          __hip_atomic_store(&dbuf[widx], wv,
                             __ATOMIC_RELAXED, __HIP_MEMORY_SCOPE_AGENT);
        }
      }
      #pragma unroll
      for (int i = 0; i < 4; ++i)
        out[((size_t)(grp*8 + hi*4 + i) * T_ + t) * H_ + jcol] = hval[i];
    }

    // ---- prefetch XG for t+1 (rides under next poll) ----
    if (t + 1 < T_) {
      #pragma unroll
      for (int i = 0; i < 4; ++i)
        if (hi < 2)
          xg[i] = (float)XG[((size_t)(t + 1)*B_ + grp*8 + hi*4 + i) * NG
                            + g*512 + jcol];
    }
  }
}

// ---------------------------------------------------------------------------
extern "C" void kernel_launch(void* const* d_in, const int* in_sizes, int n_in,
                              void* d_out, int out_size, void* d_ws, size_t ws_size,
                              hipStream_t stream)
{
  const float* x  = (const float*)d_in[0];
  const float* Wc = (const float*)d_in[1];
  const float* Wi = (const float*)d_in[2];
  const float* Wf = (const float*)d_in[3];
  const float* Wo = (const float*)d_in[4];
  const float* Uc = (const float*)d_in[5];
  const float* Ui = (const float*)d_in[6];
  const float* Uf = (const float*)d_in[7];
  const float* Uo = (const float*)d_in[8];
  const float* bc = (const float*)d_in[9];
  const float* bi = (const float*)d_in[10];
  const float* bf2= (const float*)d_in[11];
  const float* bo = (const float*)d_in[12];
  float* out = (float*)d_out;

  const size_t XG_BYTES = (size_t)T_ * B_ * NG * sizeof(_Float16);  // 128 MiB
  const size_t DB_BYTES = (size_t)2 * 8 * 4096 * sizeof(unsigned);  // 256 KiB

  if (ws_size < XG_BYTES + DB_BYTES) return;

  _Float16* XG   = (_Float16*)d_ws;
  unsigned* dbuf = (unsigned*)((char*)d_ws + XG_BYTES);

  // tag 0 == "h^0 = 0 ready"; re-zeroed every launch (kills replay aliasing)
  (void)hipMemsetAsync(dbuf, 0, DB_BYTES, stream);

  proj_kernel<<<dim3((T_*B_/64) * (NG/64)), dim3(256), 0, stream>>>(
      x, Wc, Wi, Wf, Wo, bc, bi, bf2, bo, XG);

  scan_kernel<<<dim3(256), dim3(256), 0, stream>>>(
      XG, Uc, Ui, Uf, Uo, out, dbuf);
}